// Round 10
// baseline (697.075 us; speedup 1.0000x reference)
//
#include <hip/hip_runtime.h>
#include <hip/hip_bf16.h>
#include <hip/hip_cooperative_groups.h>

namespace cg = cooperative_groups;

// ModifiedGAT, round 10:
//  - agg0g1 fusion REVERTED (r9: 88us fused vs 69+12 unfused, occupancy 51->44%,
//    barrier-serialized phase 2). agg0 is round-7's measured-69us kernel.
//  - All CSR/prep work (zero+hist+x->bf16+W-transpose+scan+scatter) merged into
//    ONE cooperative kernel with grid.sync between phases: 11 -> 6 dispatches.
//    Theory: ~100us of round-9 time is launch/drain gaps between small kernels.
//  - Pipeline: coop_build | gemm0 | agg0 | gemm1 | agg1g2 (fused) | aggF.

typedef unsigned short ushort_t;
typedef __attribute__((ext_vector_type(8))) short short8;
typedef __attribute__((ext_vector_type(4))) float f32x4;

__device__ __forceinline__ float elu_f(float x){ return x > 0.f ? x : expm1f(x); }
__device__ __forceinline__ float lrelu_f(float x){ return x > 0.f ? x : 0.2f * x; }
__device__ __forceinline__ ushort_t f2b(float f){
  union { float f; unsigned u; } v; v.f = f;
  unsigned r = v.u + 0x7fff + ((v.u >> 16) & 1);   // round-to-nearest-even
  return (ushort_t)(r >> 16);
}
__device__ __forceinline__ float b2f_lo(unsigned v){
  union { unsigned u; float f; } c; c.u = v << 16; return c.f;
}
__device__ __forceinline__ float b2f_hi(unsigned v){
  union { unsigned u; float f; } c; c.u = v & 0xffff0000u; return c.f;
}

// ---------------- cooperative build: prep + CSR in one dispatch --------------
struct BuildArgs {
  const int* ei; int* cnt;
  const float4* x4; ushort4* xb4; int n4;
  const float* W0; ushort_t* W0p;
  const float* W1; ushort_t* W1p;
  const float* W2; ushort_t* W2p;
  int* bsum; int* rowptr; int* cursor; int* esrc;
  int N, E, Etot, nb;
};

__global__ __launch_bounds__(256, 4) void build_kernel(BuildArgs p){
  cg::grid_group grid = cg::this_grid();
  __shared__ int sm[256];
  int t = threadIdx.x;
  int gid = blockIdx.x * 256 + t;
  int gsz = gridDim.x * 256;
  // ---- P0: zero cnt, x->bf16, weight transposes ----
  for(int i = gid; i < p.N; i += gsz) p.cnt[i] = 0;
  for(int i = gid; i < p.n4; i += gsz){
    float4 v = p.x4[i];
    ushort4 o;
    o.x = f2b(v.x); o.y = f2b(v.y); o.z = f2b(v.z); o.w = f2b(v.w);
    p.xb4[i] = o;
  }
  for(int i = gid; i < 256 * 256; i += gsz){
    int k = i >> 8, n = i & 255;
    p.W0p[(size_t)n * 256 + k] = f2b(p.W0[i]);
  }
  for(int i = gid; i < 256 * 64; i += gsz){
    int k = i >> 6, n = i & 63;
    p.W1p[(size_t)n * 256 + k] = f2b(p.W1[i]);
  }
  for(int i = gid; i < 64 * 64; i += gsz){
    int k = i >> 6, n = i & 63;
    p.W2p[(size_t)n * 64 + k] = f2b(p.W2[i]);
  }
  grid.sync();
  // ---- P1: degree histogram ----
  for(int e = gid; e < p.Etot; e += gsz){
    int d = (e < p.E) ? p.ei[p.E + e] : (e - p.E);
    atomicAdd(&p.cnt[d], 1);
  }
  grid.sync();
  // ---- P2: per-chunk sums (chunk = 256 nodes) ----
  for(int c = blockIdx.x; c < p.nb; c += gridDim.x){
    int i = c * 256 + t;
    sm[t] = (i < p.N) ? p.cnt[i] : 0;
    __syncthreads();
    for(int off = 128; off > 0; off >>= 1){
      if(t < off) sm[t] += sm[t + off];
      __syncthreads();
    }
    if(t == 0) p.bsum[c] = sm[0];
    __syncthreads();
  }
  grid.sync();
  // ---- P3: exclusive scan of bsum (block 0 only; nb <= 256) ----
  if(blockIdx.x == 0){
    int v = (t < p.nb) ? p.bsum[t] : 0;
    sm[t] = v;
    __syncthreads();
    for(int off = 1; off < 256; off <<= 1){
      int x = 0;
      if(t >= off) x = sm[t - off];
      __syncthreads();
      sm[t] += x;
      __syncthreads();
    }
    if(t < p.nb) p.bsum[t] = sm[t] - v;
  }
  grid.sync();
  // ---- P4: per-chunk exclusive scan -> rowptr, cursor ----
  for(int c = blockIdx.x; c < p.nb; c += gridDim.x){
    int i = c * 256 + t;
    int v = (i < p.N) ? p.cnt[i] : 0;
    sm[t] = v;
    __syncthreads();
    for(int off = 1; off < 256; off <<= 1){
      int x = 0;
      if(t >= off) x = sm[t - off];
      __syncthreads();
      sm[t] += x;
      __syncthreads();
    }
    if(i < p.N){
      int ex = sm[t] - v + p.bsum[c];
      p.rowptr[i] = ex;
      p.cursor[i] = ex;
    }
    __syncthreads();
  }
  if(gid == 0) p.rowptr[p.N] = p.Etot;
  grid.sync();
  // ---- P5: scatter (dst-sorted src list) ----
  for(int e = gid; e < p.Etot; e += gsz){
    int s, d;
    if(e < p.E){ s = p.ei[e]; d = p.ei[p.E + e]; } else { s = e - p.E; d = s; }
    int pos = atomicAdd(&p.cursor[d], 1);
    p.esrc[pos] = s;
  }
}

// ---------------- GEMM0: h0b[M,256] = bf16(x[M,256] @ W0) + logits ----------
#define SKP 264   // padded LDS k-stride (shorts)
__global__ __launch_bounds__(256) void gemm0_kernel(const ushort_t* __restrict__ A,
                                                    const ushort_t* __restrict__ Bp,
                                                    ushort_t* __restrict__ h0b,
                                                    const float* __restrict__ asrc,
                                                    const float* __restrict__ adst,
                                                    float* __restrict__ als,
                                                    float* __restrict__ ald, int M){
  __shared__ ushort_t As[32 * SKP];
  int t = threadIdx.x;
  int row0 = blockIdx.x * 32;
  {
    int c = t;
    #pragma unroll
    for(int it = 0; it < 4; it++, c += 256){
      int r = c >> 5;
      int kc = (c & 31) << 3;
      int gr = row0 + r;
      short8 v = {};
      if(gr < M) v = *(const short8*)(A + (size_t)gr * 256 + kc);
      *(short8*)(As + r * SKP + kc) = v;
    }
  }
  __syncthreads();
  int wave = t >> 6, lane = t & 63;
  int m = lane & 15, q = lane >> 4;
  int colb = wave;                   // head
  const ushort_t* Bq = Bp + (size_t)(colb * 64 + m) * 256 + q * 8;
  const ushort_t* A0 = As + m * SKP + q * 8;
  const ushort_t* A1 = As + (16 + m) * SKP + q * 8;
  f32x4 acc[2][4] = {};
  for(int k0 = 0; k0 < 256; k0 += 32){
    short8 bv[4];
    #pragma unroll
    for(int j = 0; j < 4; j++) bv[j] = *(const short8*)(Bq + (size_t)j * 16 * 256 + k0);
    short8 a0 = *(const short8*)(A0 + k0);
    short8 a1 = *(const short8*)(A1 + k0);
    #pragma unroll
    for(int j = 0; j < 4; j++){
      acc[0][j] = __builtin_amdgcn_mfma_f32_16x16x32_bf16(a0, bv[j], acc[0][j], 0, 0, 0);
      acc[1][j] = __builtin_amdgcn_mfma_f32_16x16x32_bf16(a1, bv[j], acc[1][j], 0, 0, 0);
    }
  }
  #pragma unroll
  for(int rt = 0; rt < 2; rt++){
    #pragma unroll
    for(int j = 0; j < 4; j++){
      int col = colb * 64 + j * 16 + m;
      #pragma unroll
      for(int i = 0; i < 4; i++){
        int gr = row0 + rt * 16 + q * 4 + i;
        if(gr < M) h0b[(size_t)gr * 256 + col] = f2b(acc[rt][j][i]);
      }
    }
    float vs[4] = {0,0,0,0}, vd[4] = {0,0,0,0};
    #pragma unroll
    for(int j = 0; j < 4; j++){
      int col = colb * 64 + j * 16 + m;
      float a_s = asrc[col], a_d = adst[col];
      #pragma unroll
      for(int i = 0; i < 4; i++){
        vs[i] = fmaf(acc[rt][j][i], a_s, vs[i]);
        vd[i] = fmaf(acc[rt][j][i], a_d, vd[i]);
      }
    }
    #pragma unroll
    for(int off = 8; off > 0; off >>= 1){
      #pragma unroll
      for(int i = 0; i < 4; i++){
        vs[i] += __shfl_down(vs[i], off, 16);
        vd[i] += __shfl_down(vd[i], off, 16);
      }
    }
    if(m == 0){
      #pragma unroll
      for(int i = 0; i < 4; i++){
        int gr = row0 + rt * 16 + q * 4 + i;
        if(gr < M){
          als[(size_t)gr * 4 + colb] = vs[i];
          ald[(size_t)gr * 4 + colb] = vd[i];
        }
      }
    }
  }
}

// ---------------- agg0 (round-7): wave per node, uint2 per lane --------------
__global__ __launch_bounds__(256) void agg0_kernel(const int* __restrict__ rowptr,
                                                   const int* __restrict__ esrc,
                                                   const uint2* __restrict__ h0b2,
                                                   const float4* __restrict__ als4,
                                                   const float4* __restrict__ ald4,
                                                   const float4* __restrict__ b4,
                                                   uint2* __restrict__ out2, int N){
  int t = threadIdx.x;
  int lane = t & 63;
  int n = blockIdx.x * 4 + (t >> 6);
  if(n >= N) return;
  int h = lane >> 4;
  int beg = rowptr[n], end = rowptr[n + 1];
  float adh = ((const float*)(ald4 + n))[h];
  float4 acc = make_float4(0.f, 0.f, 0.f, 0.f);
  float den = 0.f;
  for(int c0 = beg; c0 < end; c0 += 16){
    int e = c0 + (lane & 15);
    int s = n; float w = 0.f;
    if(e < end){
      s = esrc[e];
      w = expf(lrelu_f(((const float*)(als4 + s))[h] + adh));
    }
    #pragma unroll
    for(int i = 0; i < 16; i++){
      int idx = (lane & 48) + i;
      int si = __shfl(s, idx, 64);
      float wi = __shfl(w, idx, 64);
      uint2 v = h0b2[((size_t)si << 6) + lane];
      acc.x = fmaf(wi, b2f_lo(v.x), acc.x);
      acc.y = fmaf(wi, b2f_hi(v.x), acc.y);
      acc.z = fmaf(wi, b2f_lo(v.y), acc.z);
      acc.w = fmaf(wi, b2f_hi(v.y), acc.w);
      den += wi;
    }
  }
  float inv = 1.f / (den + 1e-16f);
  float4 bb = b4[lane];
  float v0 = elu_f(acc.x * inv + bb.x);
  float v1 = elu_f(acc.y * inv + bb.y);
  float v2 = elu_f(acc.z * inv + bb.z);
  float v3 = elu_f(acc.w * inv + bb.w);
  uint2 o;
  o.x = (unsigned)f2b(v0) | ((unsigned)f2b(v1) << 16);
  o.y = (unsigned)f2b(v2) | ((unsigned)f2b(v3) << 16);
  out2[((size_t)n << 6) + lane] = o;
}

// ---------------- GEMM1: g1b[M,64] = bf16(h1[M,256] @ W1) + logits ----------
__global__ __launch_bounds__(256) void mfma_gemm(const ushort_t* __restrict__ A,
                                                 const ushort_t* __restrict__ Bp,
                                                 ushort_t* __restrict__ Cp,
                                                 const float* __restrict__ asrc,
                                                 const float* __restrict__ adst,
                                                 float* __restrict__ als,
                                                 float* __restrict__ ald,
                                                 int M, int K, int NC){
  int wave = threadIdx.x >> 6;
  int lane = threadIdx.x & 63;
  int tile0 = (blockIdx.x * 4 + wave) * 2;
  if(tile0 * 16 >= M) return;
  bool two = (tile0 + 1) * 16 < M;
  int m = lane & 15, q = lane >> 4;
  const ushort_t* Ab = A + (size_t)(tile0 * 16 + m) * K + q * 8;
  const ushort_t* Bq = Bp + (size_t)m * K + q * 8;
  f32x4 acc[2][4] = {};
  for(int k0 = 0; k0 < K; k0 += 32){
    short8 bv[4];
    #pragma unroll
    for(int j = 0; j < 4; j++) bv[j] = *(const short8*)(Bq + (size_t)j * 16 * K + k0);
    short8 a0 = *(const short8*)(Ab + k0);
    #pragma unroll
    for(int j = 0; j < 4; j++)
      acc[0][j] = __builtin_amdgcn_mfma_f32_16x16x32_bf16(a0, bv[j], acc[0][j], 0, 0, 0);
    if(two){
      short8 a1 = *(const short8*)(Ab + (size_t)16 * K + k0);
      #pragma unroll
      for(int j = 0; j < 4; j++)
        acc[1][j] = __builtin_amdgcn_mfma_f32_16x16x32_bf16(a1, bv[j], acc[1][j], 0, 0, 0);
    }
  }
  #pragma unroll
  for(int r = 0; r < 2; r++){
    if(r == 1 && !two) break;
    int rowt = tile0 + r;
    #pragma unroll
    for(int j = 0; j < 4; j++){
      int col = j * 16 + m;
      #pragma unroll
      for(int i = 0; i < 4; i++){
        int rr = rowt * 16 + q * 4 + i;
        Cp[(size_t)rr * NC + col] = f2b(acc[r][j][i]);
      }
    }
    float vs[4] = {0,0,0,0}, vd[4] = {0,0,0,0};
    #pragma unroll
    for(int j = 0; j < 4; j++){
      int col = j * 16 + m;
      float a_s = asrc[col], a_d = adst[col];
      #pragma unroll
      for(int i = 0; i < 4; i++){
        vs[i] = fmaf(acc[r][j][i], a_s, vs[i]);
        vd[i] = fmaf(acc[r][j][i], a_d, vd[i]);
      }
    }
    #pragma unroll
    for(int off = 8; off > 0; off >>= 1){
      #pragma unroll
      for(int i = 0; i < 4; i++){
        vs[i] += __shfl_down(vs[i], off, 16);
        vd[i] += __shfl_down(vd[i], off, 16);
      }
    }
    if(m == 0){
      #pragma unroll
      for(int i = 0; i < 4; i++){
        int rr = rowt * 16 + q * 4 + i;
        als[rr] = vs[i];
        ald[rr] = vd[i];
      }
    }
  }
}

// ---------------- agg1-L1 + GEMM2 fused --------------------------------------
#define H2S 72    // LDS h2 tile k-stride (shorts)
__global__ __launch_bounds__(256) void agg1g2_kernel(const int* __restrict__ rowptr,
                                                     const int* __restrict__ esrc,
                                                     const unsigned* __restrict__ g1b,
                                                     const float* __restrict__ als1,
                                                     const float* __restrict__ ald1,
                                                     const float* __restrict__ b1,
                                                     const ushort_t* __restrict__ W2p,
                                                     const float* __restrict__ as2,
                                                     const float* __restrict__ ad2,
                                                     ushort_t* __restrict__ g2b,
                                                     float* __restrict__ als2,
                                                     float* __restrict__ ald2, int N){
  __shared__ ushort_t Hs[16 * H2S];
  __shared__ float aps[4][16], apd[4][16];
  int t = threadIdx.x;
  int wave = t >> 6, lane = t & 63;
  int nbase = blockIdx.x * 16;
  int half = lane >> 5;
  int p = lane & 31;
  for(int j = 0; j < 4; j++){
    int n = nbase + wave * 4 + j;
    int nl = wave * 4 + j;
    if(n < N){
      int beg = rowptr[n], end = rowptr[n + 1];
      float ad = ald1[n];
      float a0 = 0.f, a1 = 0.f, den = 0.f;
      for(int c0 = beg; c0 < end; c0 += 32){
        int e = c0 + p;
        int s = n; float w = 0.f;
        if(e < end){
          s = esrc[e];
          w = expf(lrelu_f(als1[s] + ad));
        }
        #pragma unroll
        for(int i = 0; i < 16; i++){
          int idx = 2 * i + half;
          int si = __shfl(s, idx, 64);
          float wi = __shfl(w, idx, 64);
          unsigned v = g1b[((size_t)si << 5) + p];
          a0 = fmaf(wi, b2f_lo(v), a0);
          a1 = fmaf(wi, b2f_hi(v), a1);
          den += wi;
        }
      }
      a0 += __shfl_xor(a0, 32, 64);
      a1 += __shfl_xor(a1, 32, 64);
      den += __shfl_xor(den, 32, 64);
      float inv = 1.f / (den + 1e-16f);
      float2 bb = ((const float2*)b1)[p];
      if(half == 0){
        unsigned o = (unsigned)f2b(elu_f(a0 * inv + bb.x)) |
                     ((unsigned)f2b(elu_f(a1 * inv + bb.y)) << 16);
        *(unsigned*)(Hs + nl * H2S + p * 2) = o;
      }
    }
  }
  __syncthreads();
  int m = lane & 15, q = lane >> 4;
  const ushort_t* Bw = W2p + (size_t)(wave * 16 + m) * 64 + q * 8;
  const ushort_t* Aw = Hs + m * H2S + q * 8;
  f32x4 acc = {};
  #pragma unroll
  for(int k0 = 0; k0 < 64; k0 += 32){
    short8 av = *(const short8*)(Aw + k0);
    short8 bv = *(const short8*)(Bw + k0);
    acc = __builtin_amdgcn_mfma_f32_16x16x32_bf16(av, bv, acc, 0, 0, 0);
  }
  float a_s = as2[wave * 16 + m], a_d = ad2[wave * 16 + m];
  float vs[4], vd[4];
  #pragma unroll
  for(int i = 0; i < 4; i++){
    int gn = nbase + q * 4 + i;
    if(gn < N) g2b[(size_t)gn * 64 + wave * 16 + m] = f2b(acc[i]);
    vs[i] = acc[i] * a_s;
    vd[i] = acc[i] * a_d;
  }
  #pragma unroll
  for(int off = 8; off > 0; off >>= 1){
    #pragma unroll
    for(int i = 0; i < 4; i++){
      vs[i] += __shfl_down(vs[i], off, 16);
      vd[i] += __shfl_down(vd[i], off, 16);
    }
  }
  if(m == 0){
    #pragma unroll
    for(int i = 0; i < 4; i++){
      aps[wave][q * 4 + i] = vs[i];
      apd[wave][q * 4 + i] = vd[i];
    }
  }
  __syncthreads();
  if(t < 16){
    int gn = nbase + t;
    if(gn < N){
      als2[gn] = aps[0][t] + aps[1][t] + aps[2][t] + aps[3][t];
      ald2[gn] = apd[0][t] + apd[1][t] + apd[2][t] + apd[3][t];
    }
  }
}

// ---------------- final agg (layer 2): wave per node, fp32 out ---------------
__global__ __launch_bounds__(256) void aggF_kernel(const int* __restrict__ rowptr,
                                                   const int* __restrict__ esrc,
                                                   const unsigned* __restrict__ gb,
                                                   const float* __restrict__ als,
                                                   const float* __restrict__ ald,
                                                   const float* __restrict__ b,
                                                   float2* __restrict__ outp, int N){
  int t = threadIdx.x;
  int lane = t & 63;
  int n = blockIdx.x * 4 + (t >> 6);
  if(n >= N) return;
  int half = lane >> 5;
  int p = lane & 31;
  int beg = rowptr[n], end = rowptr[n + 1];
  float ad = ald[n];
  float a0 = 0.f, a1 = 0.f, den = 0.f;
  for(int c0 = beg; c0 < end; c0 += 32){
    int e = c0 + p;
    int s = n; float w = 0.f;
    if(e < end){
      s = esrc[e];
      w = expf(lrelu_f(als[s] + ad));
    }
    #pragma unroll
    for(int i = 0; i < 16; i++){
      int idx = 2 * i + half;
      int si = __shfl(s, idx, 64);
      float wi = __shfl(w, idx, 64);
      unsigned v = gb[((size_t)si << 5) + p];
      a0 = fmaf(wi, b2f_lo(v), a0);
      a1 = fmaf(wi, b2f_hi(v), a1);
      den += wi;
    }
  }
  a0 += __shfl_xor(a0, 32, 64);
  a1 += __shfl_xor(a1, 32, 64);
  den += __shfl_xor(den, 32, 64);
  float inv = 1.f / (den + 1e-16f);
  float2 bb = ((const float2*)b)[p];
  if(half == 0){
    float2 o;
    o.x = elu_f(a0 * inv + bb.x);
    o.y = elu_f(a1 * inv + bb.y);
    outp[((size_t)n << 5) + p] = o;
  }
}

extern "C" void kernel_launch(void* const* d_in, const int* in_sizes, int n_in,
                              void* d_out, int out_size, void* d_ws, size_t ws_size,
                              hipStream_t stream){
  const float* x   = (const float*)d_in[0];
  const int*   ei  = (const int*)d_in[1];
  const float* W0  = (const float*)d_in[2];
  const float* as0 = (const float*)d_in[3];
  const float* ad0 = (const float*)d_in[4];
  const float* b0  = (const float*)d_in[5];
  const float* W1  = (const float*)d_in[6];
  const float* as1 = (const float*)d_in[7];
  const float* ad1 = (const float*)d_in[8];
  const float* b1  = (const float*)d_in[9];
  const float* W2  = (const float*)d_in[10];
  const float* as2 = (const float*)d_in[11];
  const float* ad2 = (const float*)d_in[12];
  const float* b2  = (const float*)d_in[13];
  int N = in_sizes[0] / 256;
  int E = in_sizes[1] / 2;
  int Etot = E + N;

  size_t off = 0;
  auto alc = [&](size_t bytes) -> char* {
    char* p = (char*)d_ws + off;
    off += (bytes + 255) & ~(size_t)255;
    return p;
  };
  ushort_t* xb    = (ushort_t*)alc((size_t)N * 256 * 2); // x bf16; h1b, g2b alias
  ushort_t* h0b   = (ushort_t*)alc((size_t)N * 256 * 2); // h0 bf16; g1b aliases
  float*    als   = (float*)alc((size_t)N * 4 * 4);
  float*    ald   = (float*)alc((size_t)N * 4 * 4);
  float*    als1  = (float*)alc((size_t)N * 4);
  float*    ald1  = (float*)alc((size_t)N * 4);
  float*    als2  = (float*)alc((size_t)N * 4);
  float*    ald2  = (float*)alc((size_t)N * 4);
  int*      esrc  = (int*)alc((size_t)Etot * 4);
  int*      rowptr= (int*)alc((size_t)(N + 1) * 4);
  int*      cnt   = (int*)alc((size_t)N * 4);
  int*      cursor= (int*)alc((size_t)N * 4);
  int*      bsum  = (int*)alc(256 * 4);
  ushort_t* W0p   = (ushort_t*)alc(256 * 256 * 2);
  ushort_t* W1p   = (ushort_t*)alc(256 * 64 * 2);
  ushort_t* W2p   = (ushort_t*)alc(64 * 64 * 2);

  ushort_t* h1b = xb;                      // xb dead after gemm0
  ushort_t* g1b = h0b;                     // h0b dead after agg0
  ushort_t* g2b = xb;                      // h1b dead after gemm1

  int nb = (N + 255) / 256;                // <= 256 chunks
  int g0b = (N + 31) / 32;
  int rb = ((N / 16) + 7) / 8;
  int tb = (N + 15) / 16;
  int ab = (N + 3) / 4;

  // ---- cooperative build: zero/conv/transpose | hist | scan | scatter ----
  BuildArgs pa;
  pa.ei = ei; pa.cnt = cnt;
  pa.x4 = (const float4*)x; pa.xb4 = (ushort4*)xb; pa.n4 = N * 64;
  pa.W0 = W0; pa.W0p = W0p; pa.W1 = W1; pa.W1p = W1p; pa.W2 = W2; pa.W2p = W2p;
  pa.bsum = bsum; pa.rowptr = rowptr; pa.cursor = cursor; pa.esrc = esrc;
  pa.N = N; pa.E = E; pa.Etot = Etot; pa.nb = nb;
  void* args[] = { &pa };
  hipLaunchCooperativeKernel((const void*)build_kernel, dim3(512), dim3(256),
                             args, 0, stream);

  // ---- Layer 0 ----
  gemm0_kernel<<<g0b, 256, 0, stream>>>(xb, W0p, h0b, as0, ad0, als, ald, N);
  agg0_kernel<<<ab, 256, 0, stream>>>(rowptr, esrc, (const uint2*)h0b,
                                      (const float4*)als, (const float4*)ald,
                                      (const float4*)b0, (uint2*)h1b, N);

  // ---- Layer 1 GEMM ----
  mfma_gemm<<<rb, 256, 0, stream>>>(h1b, W1p, g1b, as1, ad1, als1, ald1,
                                    N, 256, 64);

  // ---- Layer 1 agg + Layer 2 GEMM (fused) ----
  agg1g2_kernel<<<tb, 256, 0, stream>>>(rowptr, esrc, (const unsigned*)g1b,
                                        als1, ald1, b1, W2p, as2, ad2,
                                        g2b, als2, ald2, N);

  // ---- Layer 2 agg -> output ----
  aggF_kernel<<<ab, 256, 0, stream>>>(rowptr, esrc, (const unsigned*)g2b,
                                      als2, ald2, b2, (float2*)d_out, N);
}

// Round 11
// 376.738 us; speedup vs baseline: 1.8503x; 1.8503x over previous
//
#include <hip/hip_runtime.h>
#include <hip/hip_bf16.h>

// ModifiedGAT, round 11:
//  - Cooperative build REVERTED (r10: grid.sync() ~65us each on 512 blocks ->
//    410us build kernel; launch gaps are ~3-5us, grid barriers are not).
//  - Keeps r10's other plan: agg0g1 UNFUSED (r7 agg0, measured 69us, + gemm1),
//    agg1g2 fused, aggF final. scanb folded into scan2 (block computes own
//    bsum prefix) -> one fewer dispatch.
//  - Pipeline: memset | prep | blocksum | scan2 | scatter | gemm0 | agg0 |
//              gemm1 | agg1g2 | aggF  (10 dispatches).

typedef unsigned short ushort_t;
typedef __attribute__((ext_vector_type(8))) short short8;
typedef __attribute__((ext_vector_type(4))) float f32x4;

__device__ __forceinline__ float elu_f(float x){ return x > 0.f ? x : expm1f(x); }
__device__ __forceinline__ float lrelu_f(float x){ return x > 0.f ? x : 0.2f * x; }
__device__ __forceinline__ ushort_t f2b(float f){
  union { float f; unsigned u; } v; v.f = f;
  unsigned r = v.u + 0x7fff + ((v.u >> 16) & 1);   // round-to-nearest-even
  return (ushort_t)(r >> 16);
}
__device__ __forceinline__ float b2f_lo(unsigned v){
  union { unsigned u; float f; } c; c.u = v << 16; return c.f;
}
__device__ __forceinline__ float b2f_hi(unsigned v){
  union { unsigned u; float f; } c; c.u = v & 0xffff0000u; return c.f;
}

// ---------------- fused prep: hist + x->bf16 + weight transposes -------------
__global__ __launch_bounds__(256) void prep_kernel(const int* __restrict__ ei,
                                                   int* __restrict__ cnt,
                                                   const float4* __restrict__ x4,
                                                   ushort4* __restrict__ xb4, int n4,
                                                   const float* __restrict__ W0,
                                                   ushort_t* __restrict__ W0p,
                                                   const float* __restrict__ W1,
                                                   ushort_t* __restrict__ W1p,
                                                   const float* __restrict__ W2,
                                                   ushort_t* __restrict__ W2p,
                                                   int E, int Etot, int eb, int fb){
  int bid = blockIdx.x; int t = threadIdx.x;
  if(bid < eb){
    int e = bid * 256 + t;
    if(e < Etot){
      int d = (e < E) ? ei[E + e] : (e - E);
      atomicAdd(&cnt[d], 1);
    }
  } else if(bid < eb + fb){
    int i = (bid - eb) * 256 + t;
    if(i < n4){
      float4 v = x4[i];
      ushort4 o;
      o.x = f2b(v.x); o.y = f2b(v.y); o.z = f2b(v.z); o.w = f2b(v.w);
      xb4[i] = o;
    }
  } else {
    int r = bid - eb - fb;
    if(r < 256){            // W0: 256x256
      int i = r * 256 + t; int k = i >> 8, n = i & 255;
      W0p[(size_t)n * 256 + k] = f2b(W0[i]);
    } else if(r < 320){     // W1: 256x64
      int i = (r - 256) * 256 + t; int k = i >> 6, n = i & 63;
      W1p[(size_t)n * 256 + k] = f2b(W1[i]);
    } else {                // W2: 64x64
      int i = (r - 320) * 256 + t; int k = i >> 6, n = i & 63;
      W2p[(size_t)n * 64 + k] = f2b(W2[i]);
    }
  }
}

// ---------------- CSR scan -----------------------------------------------------
__global__ __launch_bounds__(256) void blocksum_kernel(const int* __restrict__ cnt,
                                                       int* __restrict__ bsum, int N){
  __shared__ int sm[256];
  int t = threadIdx.x;
  int i = blockIdx.x * 256 + t;
  sm[t] = (i < N) ? cnt[i] : 0;
  __syncthreads();
  for(int off = 128; off > 0; off >>= 1){
    if(t < off) sm[t] += sm[t + off];
    __syncthreads();
  }
  if(t == 0) bsum[blockIdx.x] = sm[0];
}

// scan2 with internal bsum prefix (scanb folded in); nb <= 256.
__global__ __launch_bounds__(256) void scan2_kernel(const int* __restrict__ cnt,
                                                    const int* __restrict__ bsum,
                                                    int* __restrict__ rowptr,
                                                    int* __restrict__ cursor,
                                                    int N, int Etot, int nb){
  __shared__ int sm[256];
  __shared__ int spfx;
  int t = threadIdx.x;
  int c = blockIdx.x;
  // prefix = sum of bsum[0..c)
  sm[t] = (t < c && t < nb) ? bsum[t] : 0;
  __syncthreads();
  for(int off = 128; off > 0; off >>= 1){
    if(t < off) sm[t] += sm[t + off];
    __syncthreads();
  }
  if(t == 0) spfx = sm[0];
  __syncthreads();
  int pfx = spfx;
  __syncthreads();
  // chunk-local exclusive scan
  int i = c * 256 + t;
  int v = (i < N) ? cnt[i] : 0;
  sm[t] = v;
  __syncthreads();
  for(int off = 1; off < 256; off <<= 1){
    int x = 0;
    if(t >= off) x = sm[t - off];
    __syncthreads();
    sm[t] += x;
    __syncthreads();
  }
  if(i < N){
    int ex = sm[t] - v + pfx;
    rowptr[i] = ex;
    cursor[i] = ex;
    if(i == N - 1) rowptr[N] = Etot;
  }
}

__global__ __launch_bounds__(256) void scatter_kernel(const int* __restrict__ ei,
                                                      int* __restrict__ cursor,
                                                      int* __restrict__ esrc,
                                                      int E, int Etot){
  int e = blockIdx.x * 256 + threadIdx.x;
  if(e >= Etot) return;
  int s, d;
  if(e < E){ s = ei[e]; d = ei[E + e]; } else { s = e - E; d = s; }
  int pos = atomicAdd(&cursor[d], 1);
  esrc[pos] = s;
}

// ---------------- GEMM0: h0b[M,256] = bf16(x[M,256] @ W0) + logits ----------
#define SKP 264   // padded LDS k-stride (shorts)
__global__ __launch_bounds__(256) void gemm0_kernel(const ushort_t* __restrict__ A,
                                                    const ushort_t* __restrict__ Bp,
                                                    ushort_t* __restrict__ h0b,
                                                    const float* __restrict__ asrc,
                                                    const float* __restrict__ adst,
                                                    float* __restrict__ als,
                                                    float* __restrict__ ald, int M){
  __shared__ ushort_t As[32 * SKP];
  int t = threadIdx.x;
  int row0 = blockIdx.x * 32;
  {
    int c = t;
    #pragma unroll
    for(int it = 0; it < 4; it++, c += 256){
      int r = c >> 5;
      int kc = (c & 31) << 3;
      int gr = row0 + r;
      short8 v = {};
      if(gr < M) v = *(const short8*)(A + (size_t)gr * 256 + kc);
      *(short8*)(As + r * SKP + kc) = v;
    }
  }
  __syncthreads();
  int wave = t >> 6, lane = t & 63;
  int m = lane & 15, q = lane >> 4;
  int colb = wave;                   // head
  const ushort_t* Bq = Bp + (size_t)(colb * 64 + m) * 256 + q * 8;
  const ushort_t* A0 = As + m * SKP + q * 8;
  const ushort_t* A1 = As + (16 + m) * SKP + q * 8;
  f32x4 acc[2][4] = {};
  for(int k0 = 0; k0 < 256; k0 += 32){
    short8 bv[4];
    #pragma unroll
    for(int j = 0; j < 4; j++) bv[j] = *(const short8*)(Bq + (size_t)j * 16 * 256 + k0);
    short8 a0 = *(const short8*)(A0 + k0);
    short8 a1 = *(const short8*)(A1 + k0);
    #pragma unroll
    for(int j = 0; j < 4; j++){
      acc[0][j] = __builtin_amdgcn_mfma_f32_16x16x32_bf16(a0, bv[j], acc[0][j], 0, 0, 0);
      acc[1][j] = __builtin_amdgcn_mfma_f32_16x16x32_bf16(a1, bv[j], acc[1][j], 0, 0, 0);
    }
  }
  #pragma unroll
  for(int rt = 0; rt < 2; rt++){
    #pragma unroll
    for(int j = 0; j < 4; j++){
      int col = colb * 64 + j * 16 + m;
      #pragma unroll
      for(int i = 0; i < 4; i++){
        int gr = row0 + rt * 16 + q * 4 + i;
        if(gr < M) h0b[(size_t)gr * 256 + col] = f2b(acc[rt][j][i]);
      }
    }
    float vs[4] = {0,0,0,0}, vd[4] = {0,0,0,0};
    #pragma unroll
    for(int j = 0; j < 4; j++){
      int col = colb * 64 + j * 16 + m;
      float a_s = asrc[col], a_d = adst[col];
      #pragma unroll
      for(int i = 0; i < 4; i++){
        vs[i] = fmaf(acc[rt][j][i], a_s, vs[i]);
        vd[i] = fmaf(acc[rt][j][i], a_d, vd[i]);
      }
    }
    #pragma unroll
    for(int off = 8; off > 0; off >>= 1){
      #pragma unroll
      for(int i = 0; i < 4; i++){
        vs[i] += __shfl_down(vs[i], off, 16);
        vd[i] += __shfl_down(vd[i], off, 16);
      }
    }
    if(m == 0){
      #pragma unroll
      for(int i = 0; i < 4; i++){
        int gr = row0 + rt * 16 + q * 4 + i;
        if(gr < M){
          als[(size_t)gr * 4 + colb] = vs[i];
          ald[(size_t)gr * 4 + colb] = vd[i];
        }
      }
    }
  }
}

// ---------------- agg0 (round-7, measured 69us): wave per node ---------------
__global__ __launch_bounds__(256) void agg0_kernel(const int* __restrict__ rowptr,
                                                   const int* __restrict__ esrc,
                                                   const uint2* __restrict__ h0b2,
                                                   const float4* __restrict__ als4,
                                                   const float4* __restrict__ ald4,
                                                   const float4* __restrict__ b4,
                                                   uint2* __restrict__ out2, int N){
  int t = threadIdx.x;
  int lane = t & 63;
  int n = blockIdx.x * 4 + (t >> 6);
  if(n >= N) return;
  int h = lane >> 4;
  int beg = rowptr[n], end = rowptr[n + 1];
  float adh = ((const float*)(ald4 + n))[h];
  float4 acc = make_float4(0.f, 0.f, 0.f, 0.f);
  float den = 0.f;
  for(int c0 = beg; c0 < end; c0 += 16){
    int e = c0 + (lane & 15);
    int s = n; float w = 0.f;
    if(e < end){
      s = esrc[e];
      w = expf(lrelu_f(((const float*)(als4 + s))[h] + adh));
    }
    #pragma unroll
    for(int i = 0; i < 16; i++){
      int idx = (lane & 48) + i;
      int si = __shfl(s, idx, 64);
      float wi = __shfl(w, idx, 64);
      uint2 v = h0b2[((size_t)si << 6) + lane];
      acc.x = fmaf(wi, b2f_lo(v.x), acc.x);
      acc.y = fmaf(wi, b2f_hi(v.x), acc.y);
      acc.z = fmaf(wi, b2f_lo(v.y), acc.z);
      acc.w = fmaf(wi, b2f_hi(v.y), acc.w);
      den += wi;
    }
  }
  float inv = 1.f / (den + 1e-16f);
  float4 bb = b4[lane];
  float v0 = elu_f(acc.x * inv + bb.x);
  float v1 = elu_f(acc.y * inv + bb.y);
  float v2 = elu_f(acc.z * inv + bb.z);
  float v3 = elu_f(acc.w * inv + bb.w);
  uint2 o;
  o.x = (unsigned)f2b(v0) | ((unsigned)f2b(v1) << 16);
  o.y = (unsigned)f2b(v2) | ((unsigned)f2b(v3) << 16);
  out2[((size_t)n << 6) + lane] = o;
}

// ---------------- GEMM1: g1b[M,64] = bf16(h1[M,256] @ W1) + logits ----------
__global__ __launch_bounds__(256) void mfma_gemm(const ushort_t* __restrict__ A,
                                                 const ushort_t* __restrict__ Bp,
                                                 ushort_t* __restrict__ Cp,
                                                 const float* __restrict__ asrc,
                                                 const float* __restrict__ adst,
                                                 float* __restrict__ als,
                                                 float* __restrict__ ald,
                                                 int M, int K, int NC){
  int wave = threadIdx.x >> 6;
  int lane = threadIdx.x & 63;
  int tile0 = (blockIdx.x * 4 + wave) * 2;
  if(tile0 * 16 >= M) return;
  bool two = (tile0 + 1) * 16 < M;
  int m = lane & 15, q = lane >> 4;
  const ushort_t* Ab = A + (size_t)(tile0 * 16 + m) * K + q * 8;
  const ushort_t* Bq = Bp + (size_t)m * K + q * 8;
  f32x4 acc[2][4] = {};
  for(int k0 = 0; k0 < K; k0 += 32){
    short8 bv[4];
    #pragma unroll
    for(int j = 0; j < 4; j++) bv[j] = *(const short8*)(Bq + (size_t)j * 16 * K + k0);
    short8 a0 = *(const short8*)(Ab + k0);
    #pragma unroll
    for(int j = 0; j < 4; j++)
      acc[0][j] = __builtin_amdgcn_mfma_f32_16x16x32_bf16(a0, bv[j], acc[0][j], 0, 0, 0);
    if(two){
      short8 a1 = *(const short8*)(Ab + (size_t)16 * K + k0);
      #pragma unroll
      for(int j = 0; j < 4; j++)
        acc[1][j] = __builtin_amdgcn_mfma_f32_16x16x32_bf16(a1, bv[j], acc[1][j], 0, 0, 0);
    }
  }
  #pragma unroll
  for(int r = 0; r < 2; r++){
    if(r == 1 && !two) break;
    int rowt = tile0 + r;
    #pragma unroll
    for(int j = 0; j < 4; j++){
      int col = j * 16 + m;
      #pragma unroll
      for(int i = 0; i < 4; i++){
        int rr = rowt * 16 + q * 4 + i;
        Cp[(size_t)rr * NC + col] = f2b(acc[r][j][i]);
      }
    }
    float vs[4] = {0,0,0,0}, vd[4] = {0,0,0,0};
    #pragma unroll
    for(int j = 0; j < 4; j++){
      int col = j * 16 + m;
      float a_s = asrc[col], a_d = adst[col];
      #pragma unroll
      for(int i = 0; i < 4; i++){
        vs[i] = fmaf(acc[r][j][i], a_s, vs[i]);
        vd[i] = fmaf(acc[r][j][i], a_d, vd[i]);
      }
    }
    #pragma unroll
    for(int off = 8; off > 0; off >>= 1){
      #pragma unroll
      for(int i = 0; i < 4; i++){
        vs[i] += __shfl_down(vs[i], off, 16);
        vd[i] += __shfl_down(vd[i], off, 16);
      }
    }
    if(m == 0){
      #pragma unroll
      for(int i = 0; i < 4; i++){
        int rr = rowt * 16 + q * 4 + i;
        als[rr] = vs[i];
        ald[rr] = vd[i];
      }
    }
  }
}

// ---------------- agg1-L1 + GEMM2 fused --------------------------------------
#define H2S 72    // LDS h2 tile k-stride (shorts)
__global__ __launch_bounds__(256) void agg1g2_kernel(const int* __restrict__ rowptr,
                                                     const int* __restrict__ esrc,
                                                     const unsigned* __restrict__ g1b,
                                                     const float* __restrict__ als1,
                                                     const float* __restrict__ ald1,
                                                     const float* __restrict__ b1,
                                                     const ushort_t* __restrict__ W2p,
                                                     const float* __restrict__ as2,
                                                     const float* __restrict__ ad2,
                                                     ushort_t* __restrict__ g2b,
                                                     float* __restrict__ als2,
                                                     float* __restrict__ ald2, int N){
  __shared__ ushort_t Hs[16 * H2S];
  __shared__ float aps[4][16], apd[4][16];
  int t = threadIdx.x;
  int wave = t >> 6, lane = t & 63;
  int nbase = blockIdx.x * 16;
  int half = lane >> 5;
  int p = lane & 31;
  for(int j = 0; j < 4; j++){
    int n = nbase + wave * 4 + j;
    int nl = wave * 4 + j;
    if(n < N){
      int beg = rowptr[n], end = rowptr[n + 1];
      float ad = ald1[n];
      float a0 = 0.f, a1 = 0.f, den = 0.f;
      for(int c0 = beg; c0 < end; c0 += 32){
        int e = c0 + p;
        int s = n; float w = 0.f;
        if(e < end){
          s = esrc[e];
          w = expf(lrelu_f(als1[s] + ad));
        }
        #pragma unroll
        for(int i = 0; i < 16; i++){
          int idx = 2 * i + half;
          int si = __shfl(s, idx, 64);
          float wi = __shfl(w, idx, 64);
          unsigned v = g1b[((size_t)si << 5) + p];
          a0 = fmaf(wi, b2f_lo(v), a0);
          a1 = fmaf(wi, b2f_hi(v), a1);
          den += wi;
        }
      }
      a0 += __shfl_xor(a0, 32, 64);
      a1 += __shfl_xor(a1, 32, 64);
      den += __shfl_xor(den, 32, 64);
      float inv = 1.f / (den + 1e-16f);
      float2 bb = ((const float2*)b1)[p];
      if(half == 0){
        unsigned o = (unsigned)f2b(elu_f(a0 * inv + bb.x)) |
                     ((unsigned)f2b(elu_f(a1 * inv + bb.y)) << 16);
        *(unsigned*)(Hs + nl * H2S + p * 2) = o;
      }
    }
  }
  __syncthreads();
  int m = lane & 15, q = lane >> 4;
  const ushort_t* Bw = W2p + (size_t)(wave * 16 + m) * 64 + q * 8;
  const ushort_t* Aw = Hs + m * H2S + q * 8;
  f32x4 acc = {};
  #pragma unroll
  for(int k0 = 0; k0 < 64; k0 += 32){
    short8 av = *(const short8*)(Aw + k0);
    short8 bv = *(const short8*)(Bw + k0);
    acc = __builtin_amdgcn_mfma_f32_16x16x32_bf16(av, bv, acc, 0, 0, 0);
  }
  float a_s = as2[wave * 16 + m], a_d = ad2[wave * 16 + m];
  float vs[4], vd[4];
  #pragma unroll
  for(int i = 0; i < 4; i++){
    int gn = nbase + q * 4 + i;
    if(gn < N) g2b[(size_t)gn * 64 + wave * 16 + m] = f2b(acc[i]);
    vs[i] = acc[i] * a_s;
    vd[i] = acc[i] * a_d;
  }
  #pragma unroll
  for(int off = 8; off > 0; off >>= 1){
    #pragma unroll
    for(int i = 0; i < 4; i++){
      vs[i] += __shfl_down(vs[i], off, 16);
      vd[i] += __shfl_down(vd[i], off, 16);
    }
  }
  if(m == 0){
    #pragma unroll
    for(int i = 0; i < 4; i++){
      aps[wave][q * 4 + i] = vs[i];
      apd[wave][q * 4 + i] = vd[i];
    }
  }
  __syncthreads();
  if(t < 16){
    int gn = nbase + t;
    if(gn < N){
      als2[gn] = aps[0][t] + aps[1][t] + aps[2][t] + aps[3][t];
      ald2[gn] = apd[0][t] + apd[1][t] + apd[2][t] + apd[3][t];
    }
  }
}

// ---------------- final agg (layer 2): wave per node, fp32 out ---------------
__global__ __launch_bounds__(256) void aggF_kernel(const int* __restrict__ rowptr,
                                                   const int* __restrict__ esrc,
                                                   const unsigned* __restrict__ gb,
                                                   const float* __restrict__ als,
                                                   const float* __restrict__ ald,
                                                   const float* __restrict__ b,
                                                   float2* __restrict__ outp, int N){
  int t = threadIdx.x;
  int lane = t & 63;
  int n = blockIdx.x * 4 + (t >> 6);
  if(n >= N) return;
  int half = lane >> 5;
  int p = lane & 31;
  int beg = rowptr[n], end = rowptr[n + 1];
  float ad = ald[n];
  float a0 = 0.f, a1 = 0.f, den = 0.f;
  for(int c0 = beg; c0 < end; c0 += 32){
    int e = c0 + p;
    int s = n; float w = 0.f;
    if(e < end){
      s = esrc[e];
      w = expf(lrelu_f(als[s] + ad));
    }
    #pragma unroll
    for(int i = 0; i < 16; i++){
      int idx = 2 * i + half;
      int si = __shfl(s, idx, 64);
      float wi = __shfl(w, idx, 64);
      unsigned v = gb[((size_t)si << 5) + p];
      a0 = fmaf(wi, b2f_lo(v), a0);
      a1 = fmaf(wi, b2f_hi(v), a1);
      den += wi;
    }
  }
  a0 += __shfl_xor(a0, 32, 64);
  a1 += __shfl_xor(a1, 32, 64);
  den += __shfl_xor(den, 32, 64);
  float inv = 1.f / (den + 1e-16f);
  float2 bb = ((const float2*)b)[p];
  if(half == 0){
    float2 o;
    o.x = elu_f(a0 * inv + bb.x);
    o.y = elu_f(a1 * inv + bb.y);
    outp[((size_t)n << 5) + p] = o;
  }
}

extern "C" void kernel_launch(void* const* d_in, const int* in_sizes, int n_in,
                              void* d_out, int out_size, void* d_ws, size_t ws_size,
                              hipStream_t stream){
  const float* x   = (const float*)d_in[0];
  const int*   ei  = (const int*)d_in[1];
  const float* W0  = (const float*)d_in[2];
  const float* as0 = (const float*)d_in[3];
  const float* ad0 = (const float*)d_in[4];
  const float* b0  = (const float*)d_in[5];
  const float* W1  = (const float*)d_in[6];
  const float* as1 = (const float*)d_in[7];
  const float* ad1 = (const float*)d_in[8];
  const float* b1  = (const float*)d_in[9];
  const float* W2  = (const float*)d_in[10];
  const float* as2 = (const float*)d_in[11];
  const float* ad2 = (const float*)d_in[12];
  const float* b2  = (const float*)d_in[13];
  int N = in_sizes[0] / 256;
  int E = in_sizes[1] / 2;
  int Etot = E + N;

  size_t off = 0;
  auto alc = [&](size_t bytes) -> char* {
    char* p = (char*)d_ws + off;
    off += (bytes + 255) & ~(size_t)255;
    return p;
  };
  ushort_t* xb    = (ushort_t*)alc((size_t)N * 256 * 2); // x bf16; h1b, g2b alias
  ushort_t* h0b   = (ushort_t*)alc((size_t)N * 256 * 2); // h0 bf16; g1b aliases
  float*    als   = (float*)alc((size_t)N * 4 * 4);
  float*    ald   = (float*)alc((size_t)N * 4 * 4);
  float*    als1  = (float*)alc((size_t)N * 4);
  float*    ald1  = (float*)alc((size_t)N * 4);
  float*    als2  = (float*)alc((size_t)N * 4);
  float*    ald2  = (float*)alc((size_t)N * 4);
  int*      esrc  = (int*)alc((size_t)Etot * 4);
  int*      rowptr= (int*)alc((size_t)(N + 1) * 4);
  int*      cnt   = (int*)alc((size_t)N * 4);
  int*      cursor= (int*)alc((size_t)N * 4);
  int*      bsum  = (int*)alc(256 * 4);
  ushort_t* W0p   = (ushort_t*)alc(256 * 256 * 2);
  ushort_t* W1p   = (ushort_t*)alc(256 * 64 * 2);
  ushort_t* W2p   = (ushort_t*)alc(64 * 64 * 2);

  ushort_t* h1b = xb;                      // xb dead after gemm0
  ushort_t* g1b = h0b;                     // h0b dead after agg0
  ushort_t* g2b = xb;                      // h1b dead after gemm1

  int nb = (N + 255) / 256;                // <= 256 chunks
  int eb = (Etot + 255) / 256;
  int fb = (N * 64 + 255) / 256;
  int g0b = (N + 31) / 32;
  int rb = ((N / 16) + 7) / 8;
  int tb = (N + 15) / 16;
  int ab = (N + 3) / 4;

  // ---- prep + CSR build ----
  hipMemsetAsync(cnt, 0, (size_t)N * 4, stream);
  prep_kernel<<<eb + fb + 336, 256, 0, stream>>>(ei, cnt, (const float4*)x,
                                                 (ushort4*)xb, N * 64,
                                                 W0, W0p, W1, W1p, W2, W2p,
                                                 E, Etot, eb, fb);
  blocksum_kernel<<<nb, 256, 0, stream>>>(cnt, bsum, N);
  scan2_kernel<<<nb, 256, 0, stream>>>(cnt, bsum, rowptr, cursor, N, Etot, nb);
  scatter_kernel<<<eb, 256, 0, stream>>>(ei, cursor, esrc, E, Etot);

  // ---- Layer 0 ----
  gemm0_kernel<<<g0b, 256, 0, stream>>>(xb, W0p, h0b, as0, ad0, als, ald, N);
  agg0_kernel<<<ab, 256, 0, stream>>>(rowptr, esrc, (const uint2*)h0b,
                                      (const float4*)als, (const float4*)ald,
                                      (const float4*)b0, (uint2*)h1b, N);

  // ---- Layer 1 GEMM ----
  mfma_gemm<<<rb, 256, 0, stream>>>(h1b, W1p, g1b, as1, ad1, als1, ald1,
                                    N, 256, 64);

  // ---- Layer 1 agg + Layer 2 GEMM (fused) ----
  agg1g2_kernel<<<tb, 256, 0, stream>>>(rowptr, esrc, (const unsigned*)g1b,
                                        als1, ald1, b1, W2p, as2, ad2,
                                        g2b, als2, ald2, N);

  // ---- Layer 2 agg -> output ----
  aggF_kernel<<<ab, 256, 0, stream>>>(rowptr, esrc, (const unsigned*)g2b,
                                      als2, ald2, b2, (float2*)d_out, N);
}